// Round 17
// baseline (175.732 us; speedup 1.0000x reference)
//
#include <hip/hip_runtime.h>
#include <math.h>

#define B_ 16
#define LC_ 512
#define LP_ 4096
#define H_ 128
#define HH_ (H_*H_)

typedef unsigned long long u64t;
typedef unsigned short u16t;
typedef __attribute__((ext_vector_type(8))) short bf16x8;
typedef __attribute__((ext_vector_type(4))) float f32x4;

__device__ __forceinline__ u16t f2bf(float f) {
    union { float f; unsigned u; } v; v.f = f;
    unsigned r = (v.u + 0x7FFFu + ((v.u >> 16) & 1u)) >> 16;
    return (u16t)r;
}
__device__ __forceinline__ float bf2f(u16t s) {
    union { unsigned u; float f; } v; v.u = ((unsigned)s) << 16; return v.f;
}
__device__ __forceinline__ float bflo(unsigned u) {
    union { unsigned u; float f; } v; v.u = u << 16; return v.f;
}
__device__ __forceinline__ float bfhi(unsigned u) {
    union { unsigned u; float f; } v; v.u = u & 0xffff0000u; return v.f;
}
// packed f32x2 -> bf16x2 (RNE), single HW instruction
__device__ __forceinline__ unsigned cvtpk2(float a, float b) {
    unsigned r;
    asm volatile("v_cvt_pk_bf16_f32 %0, %1, %2" : "=v"(r) : "v"(a), "v"(b));
    return r;
}
// fast tanh: 1 - 2/(e^2x + 1); correct at +-inf, err ~1e-7
__device__ __forceinline__ float ftanh(float x) {
    float e = __expf(2.f * x);
    return fmaf(-2.f, __builtin_amdgcn_rcpf(e + 1.f), 1.f);
}
__device__ __forceinline__ bf16x8 ldfragS(const short* base, int r, int k, int stride) {
    const u64t* p = (const u64t*)(base + (size_t)r * stride + k);
    union { bf16x8 v; u64t q[2]; } u;
    u.q[0] = p[0]; u.q[1] = p[1];
    return u.v;
}
__device__ __forceinline__ bf16x8 ldfragG(const u16t* p) {
    union { bf16x8 v; uint4 q; } u;
    u.q = *(const uint4*)p;
    return u.v;
}

// ---- fp32 W[k][n] -> transposed bf16 (hi only) [n][k] ----
__device__ __forceinline__ void wprep_body(const float* __restrict__ src,
                                           u16t* __restrict__ h, int t) {
    const int n = t >> 1, k0 = (t & 1) * 64;
#pragma unroll 4
    for (int k = 0; k < 64; ++k) {
        float v = src[(size_t)(k0 + k) * H_ + n];
        h[(size_t)n * H_ + k0 + k] = f2bf(v);
    }
}

// ---- prep: 9 weight-prep blocks + 1 zeroing block ----
__global__ __launch_bounds__(256) void prep_k(const float* __restrict__ s0,
                                              const float* __restrict__ s1,
                                              const float* __restrict__ s2,
                                              u16t* __restrict__ hi,
                                              float* __restrict__ zcp,
                                              float* __restrict__ zout) {
    const int bid = blockIdx.x, t = threadIdx.x;
    if (bid < 9) {
        const int grp = bid / 3, lay = bid % 3;
        const float* src = (grp == 0 ? s0 : grp == 1 ? s1 : s2) + (size_t)lay * HH_;
        wprep_body(src, hi + (size_t)bid * HH_, t);
    } else {
        float4 zero = make_float4(0.f, 0.f, 0.f, 0.f);
        float4* z = (float4*)zcp;
        for (int j = t; j < 3072; j += 256) z[j] = zero;
        float4* z2 = (float4*)zout;
        for (int j = t; j < 1024; j += 256) z2[j] = zero;
    }
}

// ---- staging: ROWS x 128 into bf16 LDS [row][136] (512 threads) ----
template<int ROWS>
__device__ __forceinline__ void stage_fp32(const float* __restrict__ X,
                                           short* __restrict__ Xs, int t) {
#pragma unroll
    for (int j = 0; j < ROWS / 16; ++j) {
        int lin = j * 512 + t;
        int row = lin >> 5, c4 = lin & 31;
        float4 v = ((const float4*)X)[lin];
        u64t pk = (u64t)cvtpk2(v.x, v.y) | ((u64t)cvtpk2(v.z, v.w) << 32);
        *(u64t*)(Xs + (size_t)row * 136 + c4 * 4) = pk;
    }
}
__device__ __forceinline__ void stage_bf16(const u16t* __restrict__ X,
                                           short* __restrict__ Xs, int t) {
#pragma unroll
    for (int j = 0; j < 4; ++j) {
        int lin = j * 512 + t;
        *(uint4*)(Xs + (lin >> 4) * 136 + (lin & 15) * 8) = ((const uint4*)X)[lin];
    }
}

// ---- NRG*16 x 128 GEMM core: swapped operands; W frags prefetched to regs ----
template<int NRG, bool TANH, bool BF16OUT, bool LDSOUT, bool HILO>
__device__ __forceinline__ void gemm_core(const short* __restrict__ Xs,
                                          const u16t* __restrict__ Whi,
                                          const u16t* __restrict__ Wlo,
                                          const float* __restrict__ bias,
                                          const int* __restrict__ mrow,
                                          void* __restrict__ Yrow0,
                                          short* __restrict__ projLds, int t) {
    const int l = t & 63, w = t >> 6;
    const int lm = l & 15, lk = (l >> 4) * 8, lr = (l >> 4) * 4;
    const int wcol = w * 16;
    const size_t wrow = (size_t)(wcol + lm) * H_;
    bf16x8 wh[4], wl[4];
#pragma unroll
    for (int i = 0; i < 4; ++i) wh[i] = ldfragG(Whi + wrow + i * 32 + lk);
    if (HILO) {
#pragma unroll
        for (int i = 0; i < 4; ++i) wl[i] = ldfragG(Wlo + wrow + i * 32 + lk);
    }
    f32x4 acc[NRG] = {};
#pragma unroll
    for (int i = 0; i < 4; ++i) {
#pragma unroll
        for (int rg = 0; rg < NRG; ++rg) {
            bf16x8 xb = ldfragS(Xs, rg * 16 + lm, i * 32 + lk, 136);
            acc[rg] = __builtin_amdgcn_mfma_f32_16x16x32_bf16(wh[i], xb, acc[rg], 0, 0, 0);
            if (HILO)
                acc[rg] = __builtin_amdgcn_mfma_f32_16x16x32_bf16(wl[i], xb, acc[rg], 0, 0, 0);
        }
    }
    if (LDSOUT) __syncthreads();
    const int col = wcol + lr;
    float4 bq = make_float4(0.f, 0.f, 0.f, 0.f);
    if (bias) bq = *(const float4*)(bias + col);
#pragma unroll
    for (int rg = 0; rg < NRG; ++rg) {
        const int row = rg * 16 + lm;
        float v0 = acc[rg][0] + bq.x, v1 = acc[rg][1] + bq.y;
        float v2 = acc[rg][2] + bq.z, v3 = acc[rg][3] + bq.w;
        if (TANH) { v0 = ftanh(v0); v1 = ftanh(v1); v2 = ftanh(v2); v3 = ftanh(v3); }
        if (mrow) {
            const float msc = (float)mrow[row];
            v0 *= msc; v1 *= msc; v2 *= msc; v3 *= msc;
        }
        if (BF16OUT) {
            u64t pk = (u64t)cvtpk2(v0, v1) | ((u64t)cvtpk2(v2, v3) << 32);
            *(u64t*)((u16t*)Yrow0 + (size_t)row * H_ + col) = pk;
            if (LDSOUT) *(u64t*)(projLds + (size_t)row * 136 + col) = pk;
        } else {
            float4 o; o.x = v0; o.y = v1; o.z = v2; o.w = v3;
            *(float4*)((float*)Yrow0 + (size_t)row * H_ + col) = o;
        }
    }
}

// ---- prot-split core: 128 rows x 64 cols per block; waves = 4 cols x 2 row-halves ----
__device__ __forceinline__ void gemm_core_ps(const short* __restrict__ Xs,
                                             const u16t* __restrict__ Whi,
                                             int colbase,
                                             const float* __restrict__ bias,
                                             u16t* __restrict__ Yrow0, int t) {
    const int l = t & 63, w = t >> 6;
    const int lm = l & 15, lk = (l >> 4) * 8, lr = (l >> 4) * 4;
    const int wcol = (w & 3) * 16;           // wave's 16 cols within 64-col half
    const int roff = (w >> 2) * 64;          // wave's 64-row half
    const size_t wrow = (size_t)(colbase + wcol + lm) * H_;
    bf16x8 wh[4];
#pragma unroll
    for (int i = 0; i < 4; ++i) wh[i] = ldfragG(Whi + wrow + i * 32 + lk);
    f32x4 acc[4] = {};
#pragma unroll
    for (int i = 0; i < 4; ++i) {
#pragma unroll
        for (int rg = 0; rg < 4; ++rg) {
            bf16x8 xb = ldfragS(Xs, roff + rg * 16 + lm, i * 32 + lk, 136);
            acc[rg] = __builtin_amdgcn_mfma_f32_16x16x32_bf16(wh[i], xb, acc[rg], 0, 0, 0);
        }
    }
    const int col = colbase + wcol + lr;
    float4 bq = *(const float4*)(bias + col);
#pragma unroll
    for (int rg = 0; rg < 4; ++rg) {
        const int row = roff + rg * 16 + lm;
        float v0 = ftanh(acc[rg][0] + bq.x), v1 = ftanh(acc[rg][1] + bq.y);
        float v2 = ftanh(acc[rg][2] + bq.z), v3 = ftanh(acc[rg][3] + bq.w);
        u64t pk = (u64t)cvtpk2(v0, v1) | ((u64t)cvtpk2(v2, v3) << 32);
        *(u64t*)(Yrow0 + (size_t)row * H_ + col) = pk;
    }
}

// ---- layer-fused projection GEMMs ----
// grid x: [0,128) comp 64-row tiles (proj->bil chains, full 128 cols);
//         [128,1152) prot: 512 row-tiles x 2 col-halves.
__global__ __launch_bounds__(512) void gemmB_k(const float* __restrict__ prot_feat,
                                               const float* __restrict__ comp_feat,
                                               const u16t* __restrict__ WHi,
                                               const float* __restrict__ bp,
                                               const float* __restrict__ bc,
                                               u16t* __restrict__ prot_proj,
                                               u16t* __restrict__ comp_proj,
                                               u16t* __restrict__ comp_bil) {
    extern __shared__ __align__(16) short smem[];
    const int t = threadIdx.x, bx = blockIdx.x;
    if (bx < 128) {
        short* Xs = smem;
        short* Ys = smem + 64 * 136;
        const long row0 = (long)bx * 64;              // over B*LC
        stage_fp32<64>(comp_feat + (size_t)row0 * H_, Xs, t);
        __syncthreads();
#pragma unroll 1
        for (int lay = 0; lay < 3; ++lay) {
            gemm_core<4, true, true, true, false>(Xs, WHi + (size_t)(3 + lay) * HH_,
                nullptr, bc + lay * H_, nullptr,
                comp_proj + ((size_t)lay * B_ * LC_ + row0) * H_, Ys, t);
            __syncthreads();
            gemm_core<4, false, true, false, false>(Ys, WHi + (size_t)(6 + lay) * HH_,
                nullptr, nullptr, nullptr,
                comp_bil + ((size_t)lay * B_ * LC_ + row0) * H_, nullptr, t);
        }
    } else {
        short* Xs = smem;
        const int pb = bx - 128;
        const int tile = pb >> 1, nh = pb & 1;        // 512 tiles x 2 col-halves
        const long row0 = (long)tile * 128;           // over B*LP
        stage_fp32<128>(prot_feat + (size_t)row0 * H_, Xs, t);
        __syncthreads();
#pragma unroll 1
        for (int lay = 0; lay < 3; ++lay)
            gemm_core_ps(Xs, WHi + (size_t)lay * HH_, nh * 64, bp + lay * H_,
                prot_proj + ((size_t)lay * B_ * LP_ + row0) * H_, t);
    }
}

// ---- syrk staging split into load (global->regs) and write (regs->LDS) ----
__device__ __forceinline__ void stage_load(const u16t* __restrict__ src,
                                           const int* __restrict__ maskrow,
                                           u64t (&q)[2][4], int t) {
    const int m = t & 31, kq = t >> 5;
#pragma unroll
    for (int p = 0; p < 2; ++p) {
        const int kc = p * 32 + kq * 4;
#pragma unroll
        for (int r = 0; r < 4; ++r) {
            u64t v = *(const u64t*)(src + (size_t)(kc + r) * H_ + m * 4);
            if (maskrow && !maskrow[kc + r]) v = 0;
            q[p][r] = v;
        }
    }
}
__device__ __forceinline__ void stage_write(const u64t (&q)[2][4],
                                            short* __restrict__ dst, int t) {
    const int m = t & 31, kq = t >> 5;
#pragma unroll
    for (int p = 0; p < 2; ++p) {
        const int kc = p * 32 + kq * 4;
#pragma unroll
        for (int i = 0; i < 4; ++i) {
            u64t val = ((q[p][0] >> (16 * i)) & 0xffffull)
                     | (((q[p][1] >> (16 * i)) & 0xffffull) << 16)
                     | (((q[p][2] >> (16 * i)) & 0xffffull) << 32)
                     | (((q[p][3] >> (16 * i)) & 0xffffull) << 48);
            *(u64t*)(dst + (size_t)(4 * m + i) * 68 + kc) = val;
        }
    }
}

#define SL_P 16
#define SL_C 8

// ---- combined syrk, async-staged: z<3 -> M[lay]; z>=3 -> N[lay] ----
__global__ __launch_bounds__(256) void syrkC_k(const u16t* __restrict__ prot_proj,
                                               const u16t* __restrict__ comp_bil,
                                               const u16t* __restrict__ comp_proj,
                                               const int* __restrict__ prot_mask,
                                               const int* __restrict__ comp_mask,
                                               float* __restrict__ partP,
                                               float* __restrict__ partC) {
    __shared__ __align__(16) short smem[2 * 128 * 68];
    const int t = threadIdx.x;
    const int slice = blockIdx.x, b = blockIdx.y, z = blockIdx.z;
    const bool isP = z < 3;
    const int slices = isP ? SL_P : SL_C;
    if (slice >= slices) return;
    const int lay = isP ? z : z - 3;
    const u16t* Xl = isP ? prot_proj : comp_bil;
    const u16t* Yr = isP ? prot_proj : comp_proj;
    const int* mask = isP ? prot_mask : comp_mask;
    const int Kb = isP ? LP_ : LC_;
    const int rps = Kb / slices;
    float* part = isP ? partP : partC;
    short* Xt = smem;
    short* Yt = isP ? smem : smem + 128 * 68;

    const int l = t & 63, w = t >> 6;
    const int qi = (w >> 1) * 64, qj = (w & 1) * 64;
    const int lm = l & 15, lk = (l >> 4) * 8, lr = (l >> 4) * 4;
    f32x4 acc[4][4] = {};
    const int chunks = rps >> 6;
    const size_t doff = ((size_t)lay * B_ + b) * Kb;
    const size_t moff = (size_t)b * Kb;

    u64t qx[2][4], qy[2][4];
    {
        const int k0 = slice * rps;
        stage_load(Xl + (doff + k0) * H_, mask + moff + k0, qx, t);
        if (!isP) stage_load(Yr + (doff + k0) * H_, nullptr, qy, t);
    }
    for (int c = 0; c < chunks; ++c) {
        stage_write(qx, Xt, t);
        if (!isP) stage_write(qy, Yt, t);
        __syncthreads();
        if (c + 1 < chunks) {
            const int kn = slice * rps + (c + 1) * 64;
            stage_load(Xl + (doff + kn) * H_, mask + moff + kn, qx, t);
            if (!isP) stage_load(Yr + (doff + kn) * H_, nullptr, qy, t);
        }
#pragma unroll
        for (int ks = 0; ks < 64; ks += 32) {
            bf16x8 af[4], bfr[4];
#pragma unroll
            for (int it = 0; it < 4; ++it) af[it] = ldfragS(Xt, qi + it * 16 + lm, ks + lk, 68);
#pragma unroll
            for (int jt = 0; jt < 4; ++jt) bfr[jt] = ldfragS(Yt, qj + jt * 16 + lm, ks + lk, 68);
#pragma unroll
            for (int it = 0; it < 4; ++it)
#pragma unroll
                for (int jt = 0; jt < 4; ++jt)
                    acc[it][jt] = __builtin_amdgcn_mfma_f32_16x16x32_bf16(
                        af[it], bfr[jt], acc[it][jt], 0, 0, 0);
        }
        __syncthreads();
    }

    float* pb = part + (((size_t)lay * slices + slice) * B_ + b) * HH_;
#pragma unroll
    for (int it = 0; it < 4; ++it)
#pragma unroll
        for (int jt = 0; jt < 4; ++jt)
#pragma unroll
            for (int r = 0; r < 4; ++r)
                pb[(size_t)(qi + it * 16 + lr + r) * H_ + qj + jt * 16 + lm] = acc[it][jt][r];
}

// ---- combined reduce (+fused mv, +fused layer-2 MN hi/lo transpose prep) ----
__global__ __launch_bounds__(256) void reduceC_k(const float4* __restrict__ partP,
                                                 const float4* __restrict__ partC,
                                                 const float* __restrict__ Wac,
                                                 const float* __restrict__ Wap,
                                                 float* __restrict__ vc, float* __restrict__ vp,
                                                 u16t* __restrict__ MNhi, u16t* __restrict__ MNlo) {
    const int lay = blockIdx.y, z = blockIdx.z, t = threadIdx.x;
    const int slices = z ? SL_C : SL_P;
    const size_t quarter = (size_t)B_ * HH_ / 4;
    const float4* p = (z ? partC : partP) + (size_t)lay * slices * quarter;
    const size_t idx = (size_t)blockIdx.x * 256 + t;
    float4 a = p[idx];
    for (int s = 1; s < slices; ++s) {
        float4 v = p[(size_t)s * quarter + idx];
        a.x += v.x; a.y += v.y; a.z += v.z; a.w += v.w;
    }
    const int b = (int)(idx >> 12);
    const int q = (int)(idx & 4095);
    const int row = q >> 5, c4 = q & 31;

    const float* Wv = (z ? Wap : Wac) + lay * H_;
    float4 w4 = ((const float4*)Wv)[c4];
    float s = a.x * w4.x + a.y * w4.y + a.z * w4.z + a.w * w4.w;
#pragma unroll
    for (int o = 16; o > 0; o >>= 1) s += __shfl_down(s, o, 32);
    if ((t & 31) == 0)
        (z ? vp : vc)[((size_t)lay * B_ + b) * H_ + row] = s;

    if (lay == 2) {
        u16t* hi = MNhi + ((size_t)z * B_ + b) * HH_;
        u16t* lo = MNlo + ((size_t)z * B_ + b) * HH_;
        const int colb = c4 * 4;
        float av[4] = {a.x, a.y, a.z, a.w};
#pragma unroll
        for (int j = 0; j < 4; ++j) {
            u16t hh = f2bf(av[j]);
            hi[(size_t)(colb + j) * H_ + row] = hh;
            lo[(size_t)(colb + j) * H_ + row] = f2bf(av[j] - bf2f(hh));
        }
    }
}

// ---- coalesced logits: 16-lane group per row ----
// grid (32, B, 6): z<3 prot lay z (128 rows/block); z>=3 comp lay z-3 (x<4).
__global__ __launch_bounds__(256) void logitsD_k(const u16t* __restrict__ prot_proj,
                                                 const u16t* __restrict__ comp_bil,
                                                 const int* __restrict__ prot_mask,
                                                 const int* __restrict__ comp_mask,
                                                 const float* __restrict__ vp,
                                                 const float* __restrict__ vc,
                                                 const float* __restrict__ bap,
                                                 const float* __restrict__ bac,
                                                 float* __restrict__ logp,
                                                 float* __restrict__ logc) {
    const int zz = blockIdx.z;
    const bool isP = zz < 3;
    if (!isP && blockIdx.x >= 4) return;
    const int lay = isP ? zz : zz - 3;
    const int b = blockIdx.y, t = threadIdx.x;
    const int n = isP ? LP_ : LC_;
    __shared__ float v[H_];
    if (t < 128) v[t] = (isP ? vp : vc)[((size_t)lay * B_ + b) * H_ + t];
    __syncthreads();
    const int g = t >> 4, j = t & 15;      // 16 groups x 16 lanes
    float v0 = v[j * 8 + 0], v1 = v[j * 8 + 1], v2 = v[j * 8 + 2], v3 = v[j * 8 + 3];
    float v4 = v[j * 8 + 4], v5 = v[j * 8 + 5], v6 = v[j * 8 + 6], v7 = v[j * 8 + 7];
    const u16t* feat = (isP ? prot_proj : comp_bil) + ((size_t)lay * B_ + b) * (size_t)n * H_;
    const int* mk = (isP ? prot_mask : comp_mask) + (size_t)b * n;
    const float bias = (isP ? bap : bac)[lay];
    float* out = (isP ? logp : logc) + ((size_t)lay * B_ + b) * n;
    const int r0 = blockIdx.x * 128;
#pragma unroll
    for (int it = 0; it < 8; ++it) {
        const int r = r0 + it * 16 + g;
        uint4 u = *(const uint4*)(feat + (size_t)r * H_ + j * 8);
        float acc = bflo(u.x) * v0 + bfhi(u.x) * v1
                  + bflo(u.y) * v2 + bfhi(u.y) * v3
                  + bflo(u.z) * v4 + bfhi(u.z) * v5
                  + bflo(u.w) * v6 + bfhi(u.w) * v7;
#pragma unroll
        for (int o = 8; o > 0; o >>= 1) acc += __shfl_xor(acc, o, 16);
        if (j == 0) out[r] = (float)mk[r] * acc + bias;
    }
}

// ---- combined masked softmax (faithful: max over ALL, exp*mask, denom+1e-6) ----
__global__ __launch_bounds__(256) void softmaxC_k(const float* __restrict__ logp,
                                                  const float* __restrict__ logc,
                                                  const int* __restrict__ prot_mask,
                                                  const int* __restrict__ comp_mask,
                                                  float* __restrict__ pw,
                                                  float* __restrict__ cw) {
    const int b = blockIdx.x, zz = blockIdx.y, t = threadIdx.x;
    const bool isP = zz < 3;
    const int lay = isP ? zz : zz - 3;
    const int n = isP ? LP_ : LC_;
    const float* l = (isP ? logp : logc) + ((size_t)lay * B_ + b) * n;
    const int* mk = (isP ? prot_mask : comp_mask) + (size_t)b * n;
    float* ww = (isP ? pw : cw) + ((size_t)lay * B_ + b) * n;
    __shared__ float Es[LP_];
    __shared__ float red[4];

    float mx = -1e30f;
    for (int q = t; q < n; q += 256) { float x = l[q]; Es[q] = x; mx = fmaxf(mx, x); }
#pragma unroll
    for (int o = 32; o > 0; o >>= 1) mx = fmaxf(mx, __shfl_down(mx, o, 64));
    if ((t & 63) == 0) red[t >> 6] = mx;
    __syncthreads();
    float m = fmaxf(fmaxf(red[0], red[1]), fmaxf(red[2], red[3]));
    __syncthreads();

    float s = 0.f;
    for (int q = t; q < n; q += 256) {
        float e = __expf(Es[q] - m) * (float)mk[q];
        Es[q] = e;
        s += e;
    }
#pragma unroll
    for (int o = 32; o > 0; o >>= 1) s += __shfl_down(s, o, 64);
    if ((t & 63) == 0) red[t >> 6] = s;
    __syncthreads();
    float denom = red[0] + red[1] + red[2] + red[3] + 1e-6f;
    for (int q = t; q < n; q += 256) ww[q] = Es[q] / denom;
}

// ---- combined pool ----
__global__ __launch_bounds__(256) void poolC_k(const u16t* __restrict__ prot_proj,
                                               const u16t* __restrict__ comp_proj,
                                               const float* __restrict__ pw,
                                               const float* __restrict__ cw,
                                               float* __restrict__ pp, float* __restrict__ cp) {
    const int zz = blockIdx.z;
    const bool isP = zz < 3;
    if (!isP && blockIdx.y >= 4) return;
    const int lay = isP ? zz : zz - 3;
    const int n = isP ? LP_ : LC_;
    const int chunk = isP ? 256 : 128;
    const int b = blockIdx.x, t = threadIdx.x;
    const int th = t & 63, tq = t >> 6;
    const int q0 = blockIdx.y * chunk;
    const u16t* pb = (isP ? prot_proj : comp_proj) + (((size_t)lay * B_ + b) * n + q0) * H_;
    const float* wb = (isP ? pw : cw) + ((size_t)lay * B_ + b) * n + q0;
    float a0 = 0.f, a1 = 0.f;
    for (int q = tq; q < chunk; q += 4) {
        float wq = wb[q];
        unsigned u = *(const unsigned*)(pb + (size_t)q * H_ + th * 2);
        a0 = fmaf(bflo(u), wq, a0);
        a1 = fmaf(bfhi(u), wq, a1);
    }
    float* ob = (isP ? pp : cp) + ((size_t)lay * B_ + b) * H_;
    atomicAdd(&ob[th * 2], a0);
    atomicAdd(&ob[th * 2 + 1], a1);
}

// ---- combined layer-2 contexts: z<16 comp b=z, z>=16 prot b=z-16 (hi/lo kept) ----
__global__ __launch_bounds__(512) void ctxC_k(const u16t* __restrict__ comp_bil,
                                              const u16t* __restrict__ prot_proj,
                                              const u16t* __restrict__ MNhi,
                                              const u16t* __restrict__ MNlo,
                                              const int* __restrict__ comp_mask,
                                              const int* __restrict__ prot_mask,
                                              float* __restrict__ out_cc,
                                              float* __restrict__ out_pc) {
    __shared__ __align__(16) short Xs[128 * 136];
    const int t = threadIdx.x, z = blockIdx.z;
    const bool isC = z < 16;
    if (isC && blockIdx.x >= LC_ / 128) return;
    const int b = isC ? z : z - 16;
    const int n = isC ? LC_ : LP_;
    const size_t rowoff = (size_t)b * n + (size_t)blockIdx.x * 128;
    const u16t* X = (isC ? comp_bil + (size_t)2 * B_ * LC_ * H_
                         : prot_proj + (size_t)2 * B_ * LP_ * H_) + rowoff * H_;
    const u16t* Whi = MNhi + ((size_t)(isC ? 0 : 1) * B_ + b) * HH_;
    const u16t* Wlo = MNlo + ((size_t)(isC ? 0 : 1) * B_ + b) * HH_;
    const int* mrow = (isC ? comp_mask : prot_mask) + rowoff;
    float* Y = (isC ? out_cc : out_pc) + rowoff * H_;
    stage_bf16(X, Xs, t);
    __syncthreads();
    gemm_core<8, false, false, false, true>(Xs, Whi, Wlo, nullptr, mrow, Y, nullptr, t);
}

// ---- combined final ----
__global__ void finalC_k(const float* __restrict__ cp, const float* __restrict__ pp,
                         const float* __restrict__ Wcc, const float* __restrict__ bcc,
                         const float* __restrict__ Wcp, const float* __restrict__ bcp,
                         float* __restrict__ out_cf, float* __restrict__ out_pf) {
    const int z = blockIdx.z;
    const float* pooled = z ? pp : cp;
    const float* Wcomb = z ? Wcp : Wcc;
    const float* bcomb = z ? bcp : bcc;
    float* out = z ? out_pf : out_cf;
    const int b = blockIdx.x, h = threadIdx.x, j0 = blockIdx.y * 64;
    float acc = (blockIdx.y == 0) ? bcomb[h] : 0.f;
#pragma unroll 4
    for (int j = 0; j < 64; ++j) {
        int jj = j0 + j;
        int lay = jj >> 7, hh = jj & 127;
        acc = fmaf(pooled[((size_t)lay * B_ + b) * H_ + hh], Wcomb[(size_t)jj * H_ + h], acc);
    }
    atomicAdd(&out[b * H_ + h], acc);
}

extern "C" void kernel_launch(void* const* d_in, const int* in_sizes, int n_in,
                              void* d_out, int out_size, void* d_ws, size_t ws_size,
                              hipStream_t stream) {
    const float* comp_feat = (const float*)d_in[0];
    const int*   comp_mask = (const int*)d_in[1];
    const float* prot_feat = (const float*)d_in[2];
    const int*   prot_mask = (const int*)d_in[3];
    const float* Wc      = (const float*)d_in[4];
    const float* bc      = (const float*)d_in[5];
    const float* Wp      = (const float*)d_in[6];
    const float* bp      = (const float*)d_in[7];
    const float* Wbl     = (const float*)d_in[8];
    const float* Wac     = (const float*)d_in[9];
    const float* bac     = (const float*)d_in[10];
    const float* Wap     = (const float*)d_in[11];
    const float* bap     = (const float*)d_in[12];
    const float* Wcomb_c = (const float*)d_in[13];
    const float* bcomb_c = (const float*)d_in[14];
    const float* Wcomb_p = (const float*)d_in[15];
    const float* bcomb_p = (const float*)d_in[16];

    // ---- workspace layout ----
    u16t* prot_proj = (u16t*)d_ws;                                  // 3*B*LP*H
    u16t* comp_proj = prot_proj + (size_t)3 * B_ * LP_ * H_;        // 3*B*LC*H
    u16t* comp_bil  = comp_proj + (size_t)3 * B_ * LC_ * H_;        // 3*B*LC*H
    u16t* WHi  = comp_bil + (size_t)3 * B_ * LC_ * H_;              // 9*HH
    u16t* MNhi = WHi + (size_t)9 * HH_;                             // 32*HH
    u16t* MNlo = MNhi + (size_t)32 * HH_;
    float* f = (float*)(MNlo + (size_t)32 * HH_);
    float* vc = f;    f += (size_t)3 * B_ * H_;
    float* vp = f;    f += (size_t)3 * B_ * H_;
    float* logc = f;  f += (size_t)3 * B_ * LC_;
    float* logp = f;  f += (size_t)3 * B_ * LP_;
    float* cw = f;    f += (size_t)3 * B_ * LC_;
    float* pw = f;    f += (size_t)3 * B_ * LP_;
    float* cp = f;    f += 3 * B_ * H_;
    float* pp = f;    f += 3 * B_ * H_;
    float* partP = pp + 3 * B_ * H_;                     // 3*SL_P*B*HH
    float* partC = partP + (size_t)3 * SL_P * B_ * HH_;  // 3*SL_C*B*HH

    float* out_cf = (float*)d_out;
    float* out_pf = out_cf + B_ * H_;
    float* out_cc = out_pf + B_ * H_;
    float* out_pc = out_cc + (size_t)B_ * LC_ * H_;

    // 1. weight prep (hi only) + zeroing
    prep_k<<<dim3(10), 256, 0, stream>>>(Wp, Wc, Wbl, WHi, cp, out_cf);
    // 2. projections: comp chains + col-split prot (2x TLP)
    gemmB_k<<<dim3(128 + 1024), 512, 34816, stream>>>(
        prot_feat, comp_feat, WHi, bp, bc, prot_proj, comp_proj, comp_bil);
    // 3. syrk M + N (all layers), high parallelism + async staging
    syrkC_k<<<dim3(SL_P, B_, 6), 256, 0, stream>>>(
        prot_proj, comp_bil, comp_proj, prot_mask, comp_mask, partP, partC);
    // 4. reduce + mv + layer-2 MN hi/lo prep
    reduceC_k<<<dim3(256, 3, 2), 256, 0, stream>>>(
        (const float4*)partP, (const float4*)partC, Wac, Wap, vc, vp, MNhi, MNlo);
    // 5. logits (coalesced 16-lane-group per row)
    logitsD_k<<<dim3(32, B_, 6), 256, 0, stream>>>(
        prot_proj, comp_bil, prot_mask, comp_mask, vp, vc, bap, bac, logp, logc);
    // 6. masked softmax
    softmaxC_k<<<dim3(B_, 6), 256, 0, stream>>>(logp, logc, prot_mask, comp_mask, pw, cw);
    // 7. pool
    poolC_k<<<dim3(B_, 16, 6), 256, 0, stream>>>(prot_proj, comp_proj, pw, cw, pp, cp);
    // 8. layer-2 contexts (hi/lo precision kept here)
    ctxC_k<<<dim3(LP_ / 128, 1, 32), 512, 0, stream>>>(
        comp_bil, prot_proj, MNhi, MNlo, comp_mask, prot_mask, out_cc, out_pc);
    // 9. final combine
    finalC_k<<<dim3(B_, 6, 2), 128, 0, stream>>>(
        cp, pp, Wcomb_c, bcomb_c, Wcomb_p, bcomb_p, out_cf, out_pf);
}

// Round 18
// 168.791 us; speedup vs baseline: 1.0411x; 1.0411x over previous
//
#include <hip/hip_runtime.h>
#include <math.h>

#define B_ 16
#define LC_ 512
#define LP_ 4096
#define H_ 128
#define HH_ (H_*H_)

typedef unsigned long long u64t;
typedef unsigned short u16t;
typedef __attribute__((ext_vector_type(8))) short bf16x8;
typedef __attribute__((ext_vector_type(4))) float f32x4;

__device__ __forceinline__ u16t f2bf(float f) {
    union { float f; unsigned u; } v; v.f = f;
    unsigned r = (v.u + 0x7FFFu + ((v.u >> 16) & 1u)) >> 16;
    return (u16t)r;
}
__device__ __forceinline__ float bf2f(u16t s) {
    union { unsigned u; float f; } v; v.u = ((unsigned)s) << 16; return v.f;
}
__device__ __forceinline__ float bflo(unsigned u) {
    union { unsigned u; float f; } v; v.u = u << 16; return v.f;
}
__device__ __forceinline__ float bfhi(unsigned u) {
    union { unsigned u; float f; } v; v.u = u & 0xffff0000u; return v.f;
}
// packed f32x2 -> bf16x2 (RNE), single HW instruction (non-volatile: schedulable)
__device__ __forceinline__ unsigned cvtpk2(float a, float b) {
    unsigned r;
    asm("v_cvt_pk_bf16_f32 %0, %1, %2" : "=v"(r) : "v"(a), "v"(b));
    return r;
}
// fast tanh: 1 - 2/(e^2x + 1); correct at +-inf, err ~1e-7
__device__ __forceinline__ float ftanh(float x) {
    float e = __expf(2.f * x);
    return fmaf(-2.f, __builtin_amdgcn_rcpf(e + 1.f), 1.f);
}
__device__ __forceinline__ bf16x8 ldfragS(const short* base, int r, int k, int stride) {
    const u64t* p = (const u64t*)(base + (size_t)r * stride + k);
    union { bf16x8 v; u64t q[2]; } u;
    u.q[0] = p[0]; u.q[1] = p[1];
    return u.v;
}
__device__ __forceinline__ bf16x8 ldfragG(const u16t* p) {
    union { bf16x8 v; uint4 q; } u;
    u.q = *(const uint4*)p;
    return u.v;
}

// ---- fp32 W[k][n] quarter-tile -> transposed bf16 [n][k] (32 n-cols per block) ----
__device__ __forceinline__ void wprep_q(const float* __restrict__ src,
                                        u16t* __restrict__ h, int chunk, int t) {
    const int n = chunk * 32 + (t >> 3), k0 = (t & 7) * 16;
#pragma unroll 4
    for (int k = 0; k < 16; ++k) {
        float v = src[(size_t)(k0 + k) * H_ + n];
        h[(size_t)n * H_ + k0 + k] = f2bf(v);
    }
}

// ---- prep: 36 weight-prep quarter blocks + 1 zeroing block ----
__global__ __launch_bounds__(256) void prep_k(const float* __restrict__ s0,
                                              const float* __restrict__ s1,
                                              const float* __restrict__ s2,
                                              u16t* __restrict__ hi,
                                              float* __restrict__ zcp,
                                              float* __restrict__ zout) {
    const int bid = blockIdx.x, t = threadIdx.x;
    if (bid < 36) {
        const int wsel = bid >> 2, chunk = bid & 3;
        const int grp = wsel / 3, lay = wsel % 3;
        const float* src = (grp == 0 ? s0 : grp == 1 ? s1 : s2) + (size_t)lay * HH_;
        wprep_q(src, hi + (size_t)wsel * HH_, chunk, t);
    } else {
        float4 zero = make_float4(0.f, 0.f, 0.f, 0.f);
        float4* z = (float4*)zcp;
        for (int j = t; j < 3072; j += 256) z[j] = zero;
        float4* z2 = (float4*)zout;
        for (int j = t; j < 1024; j += 256) z2[j] = zero;
    }
}

// ---- staging: ROWS x 128 into bf16 LDS [row][136] (512 threads) ----
template<int ROWS>
__device__ __forceinline__ void stage_fp32(const float* __restrict__ X,
                                           short* __restrict__ Xs, int t) {
#pragma unroll
    for (int j = 0; j < ROWS / 16; ++j) {
        int lin = j * 512 + t;
        int row = lin >> 5, c4 = lin & 31;
        float4 v = ((const float4*)X)[lin];
        u64t pk = (u64t)cvtpk2(v.x, v.y) | ((u64t)cvtpk2(v.z, v.w) << 32);
        *(u64t*)(Xs + (size_t)row * 136 + c4 * 4) = pk;
    }
}
__device__ __forceinline__ void stage_bf16(const u16t* __restrict__ X,
                                           short* __restrict__ Xs, int t) {
#pragma unroll
    for (int j = 0; j < 4; ++j) {
        int lin = j * 512 + t;
        *(uint4*)(Xs + (lin >> 4) * 136 + (lin & 15) * 8) = ((const uint4*)X)[lin];
    }
}

// ---- NRG*16 x 128 GEMM core: swapped operands; W frags prefetched to regs ----
template<int NRG, bool TANH, bool BF16OUT, bool LDSOUT, bool HILO>
__device__ __forceinline__ void gemm_core(const short* __restrict__ Xs,
                                          const u16t* __restrict__ Whi,
                                          const u16t* __restrict__ Wlo,
                                          const float* __restrict__ bias,
                                          const int* __restrict__ mrow,
                                          void* __restrict__ Yrow0,
                                          short* __restrict__ projLds, int t) {
    const int l = t & 63, w = t >> 6;
    const int lm = l & 15, lk = (l >> 4) * 8, lr = (l >> 4) * 4;
    const int wcol = w * 16;
    const size_t wrow = (size_t)(wcol + lm) * H_;
    bf16x8 wh[4], wl[4];
#pragma unroll
    for (int i = 0; i < 4; ++i) wh[i] = ldfragG(Whi + wrow + i * 32 + lk);
    if (HILO) {
#pragma unroll
        for (int i = 0; i < 4; ++i) wl[i] = ldfragG(Wlo + wrow + i * 32 + lk);
    }
    f32x4 acc[NRG] = {};
#pragma unroll
    for (int i = 0; i < 4; ++i) {
#pragma unroll
        for (int rg = 0; rg < NRG; ++rg) {
            bf16x8 xb = ldfragS(Xs, rg * 16 + lm, i * 32 + lk, 136);
            acc[rg] = __builtin_amdgcn_mfma_f32_16x16x32_bf16(wh[i], xb, acc[rg], 0, 0, 0);
            if (HILO)
                acc[rg] = __builtin_amdgcn_mfma_f32_16x16x32_bf16(wl[i], xb, acc[rg], 0, 0, 0);
        }
    }
    if (LDSOUT) __syncthreads();
    const int col = wcol + lr;
    float4 bq = make_float4(0.f, 0.f, 0.f, 0.f);
    if (bias) bq = *(const float4*)(bias + col);
#pragma unroll
    for (int rg = 0; rg < NRG; ++rg) {
        const int row = rg * 16 + lm;
        float v0 = acc[rg][0] + bq.x, v1 = acc[rg][1] + bq.y;
        float v2 = acc[rg][2] + bq.z, v3 = acc[rg][3] + bq.w;
        if (TANH) { v0 = ftanh(v0); v1 = ftanh(v1); v2 = ftanh(v2); v3 = ftanh(v3); }
        if (mrow) {
            const float msc = (float)mrow[row];
            v0 *= msc; v1 *= msc; v2 *= msc; v3 *= msc;
        }
        if (BF16OUT) {
            u64t pk = (u64t)cvtpk2(v0, v1) | ((u64t)cvtpk2(v2, v3) << 32);
            *(u64t*)((u16t*)Yrow0 + (size_t)row * H_ + col) = pk;
            if (LDSOUT) *(u64t*)(projLds + (size_t)row * 136 + col) = pk;
        } else {
            float4 o; o.x = v0; o.y = v1; o.z = v2; o.w = v3;
            *(float4*)((float*)Yrow0 + (size_t)row * H_ + col) = o;
        }
    }
}

// ---- prot-split core: 128 rows x 64 cols per block; waves = 4 cols x 2 row-halves ----
__device__ __forceinline__ void gemm_core_ps(const short* __restrict__ Xs,
                                             const u16t* __restrict__ Whi,
                                             int colbase,
                                             const float* __restrict__ bias,
                                             u16t* __restrict__ Yrow0, int t) {
    const int l = t & 63, w = t >> 6;
    const int lm = l & 15, lk = (l >> 4) * 8, lr = (l >> 4) * 4;
    const int wcol = (w & 3) * 16;
    const int roff = (w >> 2) * 64;
    const size_t wrow = (size_t)(colbase + wcol + lm) * H_;
    bf16x8 wh[4];
#pragma unroll
    for (int i = 0; i < 4; ++i) wh[i] = ldfragG(Whi + wrow + i * 32 + lk);
    f32x4 acc[4] = {};
#pragma unroll
    for (int i = 0; i < 4; ++i) {
#pragma unroll
        for (int rg = 0; rg < 4; ++rg) {
            bf16x8 xb = ldfragS(Xs, roff + rg * 16 + lm, i * 32 + lk, 136);
            acc[rg] = __builtin_amdgcn_mfma_f32_16x16x32_bf16(wh[i], xb, acc[rg], 0, 0, 0);
        }
    }
    const int col = colbase + wcol + lr;
    float4 bq = *(const float4*)(bias + col);
#pragma unroll
    for (int rg = 0; rg < 4; ++rg) {
        const int row = roff + rg * 16 + lm;
        float v0 = ftanh(acc[rg][0] + bq.x), v1 = ftanh(acc[rg][1] + bq.y);
        float v2 = ftanh(acc[rg][2] + bq.z), v3 = ftanh(acc[rg][3] + bq.w);
        u64t pk = (u64t)cvtpk2(v0, v1) | ((u64t)cvtpk2(v2, v3) << 32);
        *(u64t*)(Yrow0 + (size_t)row * H_ + col) = pk;
    }
}

// ---- layer-fused projection GEMMs ----
__global__ __launch_bounds__(512) void gemmB_k(const float* __restrict__ prot_feat,
                                               const float* __restrict__ comp_feat,
                                               const u16t* __restrict__ WHi,
                                               const float* __restrict__ bp,
                                               const float* __restrict__ bc,
                                               u16t* __restrict__ prot_proj,
                                               u16t* __restrict__ comp_proj,
                                               u16t* __restrict__ comp_bil) {
    extern __shared__ __align__(16) short smem[];
    const int t = threadIdx.x, bx = blockIdx.x;
    if (bx < 128) {
        short* Xs = smem;
        short* Ys = smem + 64 * 136;
        const long row0 = (long)bx * 64;              // over B*LC
        stage_fp32<64>(comp_feat + (size_t)row0 * H_, Xs, t);
        __syncthreads();
#pragma unroll 1
        for (int lay = 0; lay < 3; ++lay) {
            gemm_core<4, true, true, true, false>(Xs, WHi + (size_t)(3 + lay) * HH_,
                nullptr, bc + lay * H_, nullptr,
                comp_proj + ((size_t)lay * B_ * LC_ + row0) * H_, Ys, t);
            __syncthreads();
            gemm_core<4, false, true, false, false>(Ys, WHi + (size_t)(6 + lay) * HH_,
                nullptr, nullptr, nullptr,
                comp_bil + ((size_t)lay * B_ * LC_ + row0) * H_, nullptr, t);
        }
    } else {
        short* Xs = smem;
        const int pb = bx - 128;
        const int tile = pb >> 1, nh = pb & 1;        // 512 tiles x 2 col-halves
        const long row0 = (long)tile * 128;           // over B*LP
        stage_fp32<128>(prot_feat + (size_t)row0 * H_, Xs, t);
        __syncthreads();
#pragma unroll 1
        for (int lay = 0; lay < 3; ++lay)
            gemm_core_ps(Xs, WHi + (size_t)lay * HH_, nh * 64, bp + lay * H_,
                prot_proj + ((size_t)lay * B_ * LP_ + row0) * H_, t);
    }
}

// ---- syrk staging split into load (global->regs) and write (regs->LDS) ----
__device__ __forceinline__ void stage_load(const u16t* __restrict__ src,
                                           const int* __restrict__ maskrow,
                                           u64t (&q)[2][4], int t) {
    const int m = t & 31, kq = t >> 5;
#pragma unroll
    for (int p = 0; p < 2; ++p) {
        const int kc = p * 32 + kq * 4;
#pragma unroll
        for (int r = 0; r < 4; ++r) {
            u64t v = *(const u64t*)(src + (size_t)(kc + r) * H_ + m * 4);
            if (maskrow && !maskrow[kc + r]) v = 0;
            q[p][r] = v;
        }
    }
}
__device__ __forceinline__ void stage_write(const u64t (&q)[2][4],
                                            short* __restrict__ dst, int t) {
    const int m = t & 31, kq = t >> 5;
#pragma unroll
    for (int p = 0; p < 2; ++p) {
        const int kc = p * 32 + kq * 4;
#pragma unroll
        for (int i = 0; i < 4; ++i) {
            u64t val = ((q[p][0] >> (16 * i)) & 0xffffull)
                     | (((q[p][1] >> (16 * i)) & 0xffffull) << 16)
                     | (((q[p][2] >> (16 * i)) & 0xffffull) << 32)
                     | (((q[p][3] >> (16 * i)) & 0xffffull) << 48);
            *(u64t*)(dst + (size_t)(4 * m + i) * 68 + kc) = val;
        }
    }
}

#define SL_P 16
#define SL_C 8

// ---- combined syrk, async-staged: z<3 -> M[lay]; z>=3 -> N[lay] ----
__global__ __launch_bounds__(256) void syrkC_k(const u16t* __restrict__ prot_proj,
                                               const u16t* __restrict__ comp_bil,
                                               const u16t* __restrict__ comp_proj,
                                               const int* __restrict__ prot_mask,
                                               const int* __restrict__ comp_mask,
                                               float* __restrict__ partP,
                                               float* __restrict__ partC) {
    __shared__ __align__(16) short smem[2 * 128 * 68];
    const int t = threadIdx.x;
    const int slice = blockIdx.x, b = blockIdx.y, z = blockIdx.z;
    const bool isP = z < 3;
    const int slices = isP ? SL_P : SL_C;
    if (slice >= slices) return;
    const int lay = isP ? z : z - 3;
    const u16t* Xl = isP ? prot_proj : comp_bil;
    const u16t* Yr = isP ? prot_proj : comp_proj;
    const int* mask = isP ? prot_mask : comp_mask;
    const int Kb = isP ? LP_ : LC_;
    const int rps = Kb / slices;
    float* part = isP ? partP : partC;
    short* Xt = smem;
    short* Yt = isP ? smem : smem + 128 * 68;

    const int l = t & 63, w = t >> 6;
    const int qi = (w >> 1) * 64, qj = (w & 1) * 64;
    const int lm = l & 15, lk = (l >> 4) * 8, lr = (l >> 4) * 4;
    f32x4 acc[4][4] = {};
    const int chunks = rps >> 6;
    const size_t doff = ((size_t)lay * B_ + b) * Kb;
    const size_t moff = (size_t)b * Kb;

    u64t qx[2][4], qy[2][4];
    {
        const int k0 = slice * rps;
        stage_load(Xl + (doff + k0) * H_, mask + moff + k0, qx, t);
        if (!isP) stage_load(Yr + (doff + k0) * H_, nullptr, qy, t);
    }
    for (int c = 0; c < chunks; ++c) {
        stage_write(qx, Xt, t);
        if (!isP) stage_write(qy, Yt, t);
        __syncthreads();
        if (c + 1 < chunks) {
            const int kn = slice * rps + (c + 1) * 64;
            stage_load(Xl + (doff + kn) * H_, mask + moff + kn, qx, t);
            if (!isP) stage_load(Yr + (doff + kn) * H_, nullptr, qy, t);
        }
#pragma unroll
        for (int ks = 0; ks < 64; ks += 32) {
            bf16x8 af[4], bfr[4];
#pragma unroll
            for (int it = 0; it < 4; ++it) af[it] = ldfragS(Xt, qi + it * 16 + lm, ks + lk, 68);
#pragma unroll
            for (int jt = 0; jt < 4; ++jt) bfr[jt] = ldfragS(Yt, qj + jt * 16 + lm, ks + lk, 68);
#pragma unroll
            for (int it = 0; it < 4; ++it)
#pragma unroll
                for (int jt = 0; jt < 4; ++jt)
                    acc[it][jt] = __builtin_amdgcn_mfma_f32_16x16x32_bf16(
                        af[it], bfr[jt], acc[it][jt], 0, 0, 0);
        }
        __syncthreads();
    }

    float* pb = part + (((size_t)lay * slices + slice) * B_ + b) * HH_;
#pragma unroll
    for (int it = 0; it < 4; ++it)
#pragma unroll
        for (int jt = 0; jt < 4; ++jt)
#pragma unroll
            for (int r = 0; r < 4; ++r)
                pb[(size_t)(qi + it * 16 + lr + r) * H_ + qj + jt * 16 + lm] = acc[it][jt][r];
}

// ---- combined reduce (+fused mv, +fused layer-2 MN hi/lo transpose prep) ----
__global__ __launch_bounds__(256) void reduceC_k(const float4* __restrict__ partP,
                                                 const float4* __restrict__ partC,
                                                 const float* __restrict__ Wac,
                                                 const float* __restrict__ Wap,
                                                 float* __restrict__ vc, float* __restrict__ vp,
                                                 u16t* __restrict__ MNhi, u16t* __restrict__ MNlo) {
    const int lay = blockIdx.y, z = blockIdx.z, t = threadIdx.x;
    const int slices = z ? SL_C : SL_P;
    const size_t quarter = (size_t)B_ * HH_ / 4;
    const float4* p = (z ? partC : partP) + (size_t)lay * slices * quarter;
    const size_t idx = (size_t)blockIdx.x * 256 + t;
    float4 a = p[idx];
    for (int s = 1; s < slices; ++s) {
        float4 v = p[(size_t)s * quarter + idx];
        a.x += v.x; a.y += v.y; a.z += v.z; a.w += v.w;
    }
    const int b = (int)(idx >> 12);
    const int q = (int)(idx & 4095);
    const int row = q >> 5, c4 = q & 31;

    const float* Wv = (z ? Wap : Wac) + lay * H_;
    float4 w4 = ((const float4*)Wv)[c4];
    float s = a.x * w4.x + a.y * w4.y + a.z * w4.z + a.w * w4.w;
#pragma unroll
    for (int o = 16; o > 0; o >>= 1) s += __shfl_down(s, o, 32);
    if ((t & 31) == 0)
        (z ? vp : vc)[((size_t)lay * B_ + b) * H_ + row] = s;

    if (lay == 2) {
        u16t* hi = MNhi + ((size_t)z * B_ + b) * HH_;
        u16t* lo = MNlo + ((size_t)z * B_ + b) * HH_;
        const int colb = c4 * 4;
        float av[4] = {a.x, a.y, a.z, a.w};
#pragma unroll
        for (int j = 0; j < 4; ++j) {
            u16t hh = f2bf(av[j]);
            hi[(size_t)(colb + j) * H_ + row] = hh;
            lo[(size_t)(colb + j) * H_ + row] = f2bf(av[j] - bf2f(hh));
        }
    }
}

// ---- fused logits + layer-2 contexts (independent work, one dispatch) ----
// grid (32, 16, 8), 512 threads:
//   z<6: logits (z<3 prot lay z, all x; z>=3 comp lay z-3, x<4), b = y.
//   z==6: ctx comp, b = y, x < 4.   z==7: ctx prot, b = y, all x.
__global__ __launch_bounds__(512) void lgctx_k(const u16t* __restrict__ prot_proj,
                                               const u16t* __restrict__ comp_bil,
                                               const u16t* __restrict__ MNhi,
                                               const u16t* __restrict__ MNlo,
                                               const int* __restrict__ prot_mask,
                                               const int* __restrict__ comp_mask,
                                               const float* __restrict__ vp,
                                               const float* __restrict__ vc,
                                               const float* __restrict__ bap,
                                               const float* __restrict__ bac,
                                               float* __restrict__ logp,
                                               float* __restrict__ logc,
                                               float* __restrict__ out_cc,
                                               float* __restrict__ out_pc) {
    __shared__ __align__(16) short Xs[128 * 136];
    const int x = blockIdx.x, b = blockIdx.y, z = blockIdx.z, t = threadIdx.x;
    if (z < 6) {
        const bool isP = z < 3;
        if (!isP && x >= 4) return;
        const int lay = isP ? z : z - 3;
        const int n = isP ? LP_ : LC_;
        float* v = (float*)Xs;
        if (t < 128) v[t] = (isP ? vp : vc)[((size_t)lay * B_ + b) * H_ + t];
        __syncthreads();
        const int g = t >> 4, j = t & 15;      // 32 groups x 16 lanes
        float v0 = v[j * 8 + 0], v1 = v[j * 8 + 1], v2 = v[j * 8 + 2], v3 = v[j * 8 + 3];
        float v4 = v[j * 8 + 4], v5 = v[j * 8 + 5], v6 = v[j * 8 + 6], v7 = v[j * 8 + 7];
        const u16t* feat = (isP ? prot_proj : comp_bil) + ((size_t)lay * B_ + b) * (size_t)n * H_;
        const int* mk = (isP ? prot_mask : comp_mask) + (size_t)b * n;
        const float bias = (isP ? bap : bac)[lay];
        float* out = (isP ? logp : logc) + ((size_t)lay * B_ + b) * n;
        const int r0 = x * 128;
#pragma unroll
        for (int it = 0; it < 4; ++it) {
            const int r = r0 + it * 32 + g;
            uint4 u = *(const uint4*)(feat + (size_t)r * H_ + j * 8);
            float acc = bflo(u.x) * v0 + bfhi(u.x) * v1
                      + bflo(u.y) * v2 + bfhi(u.y) * v3
                      + bflo(u.z) * v4 + bfhi(u.z) * v5
                      + bflo(u.w) * v6 + bfhi(u.w) * v7;
#pragma unroll
            for (int o = 8; o > 0; o >>= 1) acc += __shfl_xor(acc, o, 16);
            if (j == 0) out[r] = (float)mk[r] * acc + bias;
        }
    } else {
        const bool isC = (z == 6);
        if (isC && x >= LC_ / 128) return;
        const int n = isC ? LC_ : LP_;
        const size_t rowoff = (size_t)b * n + (size_t)x * 128;
        const u16t* X = (isC ? comp_bil + (size_t)2 * B_ * LC_ * H_
                             : prot_proj + (size_t)2 * B_ * LP_ * H_) + rowoff * H_;
        const u16t* Whi = MNhi + ((size_t)(isC ? 0 : 1) * B_ + b) * HH_;
        const u16t* Wlo = MNlo + ((size_t)(isC ? 0 : 1) * B_ + b) * HH_;
        const int* mrow = (isC ? comp_mask : prot_mask) + rowoff;
        float* Y = (isC ? out_cc : out_pc) + rowoff * H_;
        stage_bf16(X, Xs, t);
        __syncthreads();
        gemm_core<8, false, false, false, true>(Xs, Whi, Wlo, nullptr, mrow, Y, nullptr, t);
    }
}

// ---- combined masked softmax (faithful: max over ALL, exp*mask, denom+1e-6) ----
__global__ __launch_bounds__(256) void softmaxC_k(const float* __restrict__ logp,
                                                  const float* __restrict__ logc,
                                                  const int* __restrict__ prot_mask,
                                                  const int* __restrict__ comp_mask,
                                                  float* __restrict__ pw,
                                                  float* __restrict__ cw) {
    const int b = blockIdx.x, zz = blockIdx.y, t = threadIdx.x;
    const bool isP = zz < 3;
    const int lay = isP ? zz : zz - 3;
    const int n = isP ? LP_ : LC_;
    const float* l = (isP ? logp : logc) + ((size_t)lay * B_ + b) * n;
    const int* mk = (isP ? prot_mask : comp_mask) + (size_t)b * n;
    float* ww = (isP ? pw : cw) + ((size_t)lay * B_ + b) * n;
    __shared__ float Es[LP_];
    __shared__ float red[4];

    float mx = -1e30f;
    for (int q = t; q < n; q += 256) { float x = l[q]; Es[q] = x; mx = fmaxf(mx, x); }
#pragma unroll
    for (int o = 32; o > 0; o >>= 1) mx = fmaxf(mx, __shfl_down(mx, o, 64));
    if ((t & 63) == 0) red[t >> 6] = mx;
    __syncthreads();
    float m = fmaxf(fmaxf(red[0], red[1]), fmaxf(red[2], red[3]));
    __syncthreads();

    float s = 0.f;
    for (int q = t; q < n; q += 256) {
        float e = __expf(Es[q] - m) * (float)mk[q];
        Es[q] = e;
        s += e;
    }
#pragma unroll
    for (int o = 32; o > 0; o >>= 1) s += __shfl_down(s, o, 64);
    if ((t & 63) == 0) red[t >> 6] = s;
    __syncthreads();
    float denom = red[0] + red[1] + red[2] + red[3] + 1e-6f;
    for (int q = t; q < n; q += 256) ww[q] = Es[q] / denom;
}

// ---- combined pool ----
__global__ __launch_bounds__(256) void poolC_k(const u16t* __restrict__ prot_proj,
                                               const u16t* __restrict__ comp_proj,
                                               const float* __restrict__ pw,
                                               const float* __restrict__ cw,
                                               float* __restrict__ pp, float* __restrict__ cp) {
    const int zz = blockIdx.z;
    const bool isP = zz < 3;
    if (!isP && blockIdx.y >= 4) return;
    const int lay = isP ? zz : zz - 3;
    const int n = isP ? LP_ : LC_;
    const int chunk = isP ? 256 : 128;
    const int b = blockIdx.x, t = threadIdx.x;
    const int th = t & 63, tq = t >> 6;
    const int q0 = blockIdx.y * chunk;
    const u16t* pb = (isP ? prot_proj : comp_proj) + (((size_t)lay * B_ + b) * n + q0) * H_;
    const float* wb = (isP ? pw : cw) + ((size_t)lay * B_ + b) * n + q0;
    float a0 = 0.f, a1 = 0.f;
    for (int q = tq; q < chunk; q += 4) {
        float wq = wb[q];
        unsigned u = *(const unsigned*)(pb + (size_t)q * H_ + th * 2);
        a0 = fmaf(bflo(u), wq, a0);
        a1 = fmaf(bfhi(u), wq, a1);
    }
    float* ob = (isP ? pp : cp) + ((size_t)lay * B_ + b) * H_;
    atomicAdd(&ob[th * 2], a0);
    atomicAdd(&ob[th * 2 + 1], a1);
}

// ---- combined final ----
__global__ void finalC_k(const float* __restrict__ cp, const float* __restrict__ pp,
                         const float* __restrict__ Wcc, const float* __restrict__ bcc,
                         const float* __restrict__ Wcp, const float* __restrict__ bcp,
                         float* __restrict__ out_cf, float* __restrict__ out_pf) {
    const int z = blockIdx.z;
    const float* pooled = z ? pp : cp;
    const float* Wcomb = z ? Wcp : Wcc;
    const float* bcomb = z ? bcp : bcc;
    float* out = z ? out_pf : out_cf;
    const int b = blockIdx.x, h = threadIdx.x, j0 = blockIdx.y * 64;
    float acc = (blockIdx.y == 0) ? bcomb[h] : 0.f;
#pragma unroll 4
    for (int j = 0; j < 64; ++j) {
        int jj = j0 + j;
        int lay = jj >> 7, hh = jj & 127;
        acc = fmaf(pooled[((size_t)lay * B_ + b) * H_ + hh], Wcomb[(size_t)jj * H_ + h], acc);
    }
    atomicAdd(&out[b * H_ + h], acc);
}

extern "C" void kernel_launch(void* const* d_in, const int* in_sizes, int n_in,
                              void* d_out, int out_size, void* d_ws, size_t ws_size,
                              hipStream_t stream) {
    const float* comp_feat = (const float*)d_in[0];
    const int*   comp_mask = (const int*)d_in[1];
    const float* prot_feat = (const float*)d_in[2];
    const int*   prot_mask = (const int*)d_in[3];
    const float* Wc      = (const float*)d_in[4];
    const float* bc      = (const float*)d_in[5];
    const float* Wp      = (const float*)d_in[6];
    const float* bp      = (const float*)d_in[7];
    const float* Wbl     = (const float*)d_in[8];
    const float* Wac     = (const float*)d_in[9];
    const float* bac     = (const float*)d_in[10];
    const float* Wap     = (const float*)d_in[11];
    const float* bap     = (const float*)d_in[12];
    const float* Wcomb_c = (const float*)d_in[13];
    const float* bcomb_c = (const float*)d_in[14];
    const float* Wcomb_p = (const float*)d_in[15];
    const float* bcomb_p = (const float*)d_in[16];

    // ---- workspace layout ----
    u16t* prot_proj = (u16t*)d_ws;                                  // 3*B*LP*H
    u16t* comp_proj = prot_proj + (size_t)3 * B_ * LP_ * H_;        // 3*B*LC*H
    u16t* comp_bil  = comp_proj + (size_t)3 * B_ * LC_ * H_;        // 3*B*LC*H
    u16t* WHi  = comp_bil + (size_t)3 * B_ * LC_ * H_;              // 9*HH
    u16t* MNhi = WHi + (size_t)9 * HH_;                             // 32*HH
    u16t* MNlo = MNhi + (size_t)32 * HH_;
    float* f = (float*)(MNlo + (size_t)32 * HH_);
    float* vc = f;    f += (size_t)3 * B_ * H_;
    float* vp = f;    f += (size_t)3 * B_ * H_;
    float* logc = f;  f += (size_t)3 * B_ * LC_;
    float* logp = f;  f += (size_t)3 * B_ * LP_;
    float* cw = f;    f += (size_t)3 * B_ * LC_;
    float* pw = f;    f += (size_t)3 * B_ * LP_;
    float* cp = f;    f += 3 * B_ * H_;
    float* pp = f;    f += 3 * B_ * H_;
    float* partP = pp + 3 * B_ * H_;                     // 3*SL_P*B*HH
    float* partC = partP + (size_t)3 * SL_P * B_ * HH_;  // 3*SL_C*B*HH

    float* out_cf = (float*)d_out;
    float* out_pf = out_cf + B_ * H_;
    float* out_cc = out_pf + B_ * H_;
    float* out_pc = out_cc + (size_t)B_ * LC_ * H_;

    // 1. weight prep (quarter-tiles, 37 blocks) + zeroing
    prep_k<<<dim3(37), 256, 0, stream>>>(Wp, Wc, Wbl, WHi, cp, out_cf);
    // 2. projections: comp chains + col-split prot
    gemmB_k<<<dim3(128 + 1024), 512, 34816, stream>>>(
        prot_feat, comp_feat, WHi, bp, bc, prot_proj, comp_proj, comp_bil);
    // 3. syrk M + N (all layers), high parallelism + async staging
    syrkC_k<<<dim3(SL_P, B_, 6), 256, 0, stream>>>(
        prot_proj, comp_bil, comp_proj, prot_mask, comp_mask, partP, partC);
    // 4. reduce + mv + layer-2 MN hi/lo prep
    reduceC_k<<<dim3(256, 3, 2), 256, 0, stream>>>(
        (const float4*)partP, (const float4*)partC, Wac, Wap, vc, vp, MNhi, MNlo);
    // 5. logits + layer-2 contexts fused (independent work, co-resident)
    lgctx_k<<<dim3(32, B_, 8), 512, 0, stream>>>(
        prot_proj, comp_bil, MNhi, MNlo, prot_mask, comp_mask,
        vp, vc, bap, bac, logp, logc, out_cc, out_pc);
    // 6. masked softmax
    softmaxC_k<<<dim3(B_, 6), 256, 0, stream>>>(logp, logc, prot_mask, comp_mask, pw, cw);
    // 7. pool
    poolC_k<<<dim3(B_, 16, 6), 256, 0, stream>>>(prot_proj, comp_proj, pw, cw, pp, cp);
    // 8. final combine
    finalC_k<<<dim3(B_, 6, 2), 128, 0, stream>>>(
        cp, pp, Wcomb_c, bcomb_c, Wcomb_p, bcomb_p, out_cf, out_pf);
}